// Round 1
// baseline (10403.282 us; speedup 1.0000x reference)
//
#include <hip/hip_runtime.h>

#define B_ 512
#define S_ 128
#define T_ 128
#define D_ 512
#define V_ 128

typedef __attribute__((ext_vector_type(8))) short s16x8;
typedef __attribute__((ext_vector_type(4))) short s16x4;
typedef __attribute__((ext_vector_type(4))) float f32x4;

__device__ __forceinline__ float b2f(unsigned short h) {
    union { unsigned int u; float f; } x;
    x.u = ((unsigned int)h) << 16;
    return x.f;
}
__device__ __forceinline__ unsigned short f2b(float f) {
    union { float f; unsigned int u; } x;
    x.f = f;
    unsigned int u = x.u;
    u += 0x7FFFu + ((u >> 16) & 1u);
    return (unsigned short)(u >> 16);
}
__device__ __forceinline__ float sigm(float x) { return 1.0f / (1.0f + __expf(-x)); }
__device__ __forceinline__ float tanh_fast(float x) {
    float e = __expf(-2.0f * fabsf(x));
    float r = (1.0f - e) / (1.0f + e);
    return copysignf(r, x);
}

// ---------------- generic 64x64 MFMA GEMM: C = A[M,K](bf16) @ Bt[N,K]^T (bf16) + bias ----------------
template<bool OUT_BF16>
__global__ __launch_bounds__(256)
void gemm64(const short* __restrict__ A, const short* __restrict__ Bt,
            const float* __restrict__ bias, void* __restrict__ Cp,
            int M, int N, int K)
{
    __shared__ __align__(16) short As[64][72];
    __shared__ __align__(16) short Bs[64][72];
    const int t = threadIdx.x;
    const int lane = t & 63, wave = t >> 6;
    const int wr = wave >> 1, wc = wave & 1;
    const int lrow = lane & 15, kq = lane >> 4;
    const int m0 = blockIdx.y * 64, n0 = blockIdx.x * 64;
    const int srow = t >> 3, sseg = t & 7;

    f32x4 acc[2][2] = {};
    for (int k0 = 0; k0 < K; k0 += 64) {
        s16x8 va0 = *(const s16x8*)(A + (size_t)(m0 + srow) * K + k0 + sseg * 8);
        s16x8 va1 = *(const s16x8*)(A + (size_t)(m0 + srow + 32) * K + k0 + sseg * 8);
        s16x8 vb0 = *(const s16x8*)(Bt + (size_t)(n0 + srow) * K + k0 + sseg * 8);
        s16x8 vb1 = *(const s16x8*)(Bt + (size_t)(n0 + srow + 32) * K + k0 + sseg * 8);
        __syncthreads();
        *(s16x8*)(&As[srow][sseg * 8]) = va0;
        *(s16x8*)(&As[srow + 32][sseg * 8]) = va1;
        *(s16x8*)(&Bs[srow][sseg * 8]) = vb0;
        *(s16x8*)(&Bs[srow + 32][sseg * 8]) = vb1;
        __syncthreads();
        for (int kk = 0; kk < 64; kk += 32) {
            s16x8 af[2], bf[2];
            af[0] = *(const s16x8*)(&As[wr * 32 + lrow][kk + kq * 8]);
            af[1] = *(const s16x8*)(&As[wr * 32 + 16 + lrow][kk + kq * 8]);
            bf[0] = *(const s16x8*)(&Bs[wc * 32 + lrow][kk + kq * 8]);
            bf[1] = *(const s16x8*)(&Bs[wc * 32 + 16 + lrow][kk + kq * 8]);
            for (int m2 = 0; m2 < 2; ++m2)
                for (int n2 = 0; n2 < 2; ++n2)
                    acc[m2][n2] = __builtin_amdgcn_mfma_f32_16x16x32_bf16(af[m2], bf[n2], acc[m2][n2], 0, 0, 0);
        }
    }
    for (int m2 = 0; m2 < 2; ++m2)
        for (int n2 = 0; n2 < 2; ++n2) {
            int col = n0 + wc * 32 + n2 * 16 + lrow;
            float bvv = bias ? bias[col] : 0.0f;
            for (int j = 0; j < 4; ++j) {
                int row = m0 + wr * 32 + m2 * 16 + kq * 4 + j;
                float v = acc[m2][n2][j] + bvv;
                if (OUT_BF16) ((short*)Cp)[(size_t)row * N + col] = (short)f2b(v);
                else          ((float*)Cp)[(size_t)row * N + col] = v;
            }
        }
}

// ---------------- output GEMM (M=512,N=128,K=512) with fused log_softmax ----------------
__global__ __launch_bounds__(256)
void out_lsm(const short* __restrict__ A, const short* __restrict__ Bt,
             const float* __restrict__ bias, float* __restrict__ outp, int tstep)
{
    __shared__ __align__(16) short As[64][72];
    __shared__ __align__(16) short Bs[128][72];
    const int t = threadIdx.x;
    const int lane = t & 63, wave = t >> 6;
    const int lrow = lane & 15, kq = lane >> 4;
    const int m0 = blockIdx.x * 64;
    const int srow = t >> 3, sseg = t & 7;
    f32x4 acc[8] = {};
    for (int k0 = 0; k0 < 512; k0 += 64) {
        s16x8 va0 = *(const s16x8*)(A + (size_t)(m0 + srow) * 512 + k0 + sseg * 8);
        s16x8 va1 = *(const s16x8*)(A + (size_t)(m0 + srow + 32) * 512 + k0 + sseg * 8);
        s16x8 vb[4];
        for (int p = 0; p < 4; ++p)
            vb[p] = *(const s16x8*)(Bt + (size_t)(srow + p * 32) * 512 + k0 + sseg * 8);
        __syncthreads();
        *(s16x8*)(&As[srow][sseg * 8]) = va0;
        *(s16x8*)(&As[srow + 32][sseg * 8]) = va1;
        for (int p = 0; p < 4; ++p) *(s16x8*)(&Bs[srow + p * 32][sseg * 8]) = vb[p];
        __syncthreads();
        for (int kk = 0; kk < 64; kk += 32) {
            s16x8 a = *(const s16x8*)(&As[wave * 16 + lrow][kk + kq * 8]);
            for (int f = 0; f < 8; ++f) {
                s16x8 b = *(const s16x8*)(&Bs[f * 16 + lrow][kk + kq * 8]);
                acc[f] = __builtin_amdgcn_mfma_f32_16x16x32_bf16(a, b, acc[f], 0, 0, 0);
            }
        }
    }
    float colb[8];
    for (int f = 0; f < 8; ++f) colb[f] = bias[f * 16 + lrow];
    for (int j = 0; j < 4; ++j) {
        float v[8]; float mx = -1e30f;
        for (int f = 0; f < 8; ++f) { v[f] = acc[f][j] + colb[f]; mx = fmaxf(mx, v[f]); }
        for (int o = 1; o < 16; o <<= 1) mx = fmaxf(mx, __shfl_xor(mx, o));
        float sum = 0.f;
        for (int f = 0; f < 8; ++f) sum += __expf(v[f] - mx);
        for (int o = 1; o < 16; o <<= 1) sum += __shfl_xor(sum, o);
        float lse = mx + __logf(sum);
        int row = m0 + wave * 16 + kq * 4 + j;
        float* orow = outp + ((size_t)row * T_ + tstep) * V_;
        for (int f = 0; f < 8; ++f) orow[f * 16 + lrow] = v[f] - lse;
    }
}

// ---------------- attention: scores + softmax + ctx, one block per batch row ----------------
__global__ __launch_bounds__(256)
void attn_step(const float* __restrict__ q, const short* __restrict__ kp,
               const short* __restrict__ eall, const float* __restrict__ Va,
               const float* __restrict__ bvp, short* __restrict__ xcat,
               float* __restrict__ attn_out, int tstep)
{
    const int b = blockIdx.x;
    const int t = threadIdx.x, lane = t & 63, wave = t >> 6;
    __shared__ float sc[S_];
    __shared__ float wbuf[S_];
    __shared__ float red[2];
    const int d0 = lane * 8;
    float qr[8], var[8];
    const float* qrow = q + (size_t)b * D_ + d0;
    for (int j = 0; j < 8; ++j) { qr[j] = qrow[j]; var[j] = Va[d0 + j]; }
    const float bvv = bvp[0];
    for (int i = 0; i < 32; ++i) {
        int s = wave * 32 + i;
        s16x8 kv = *(const s16x8*)(kp + ((size_t)b * S_ + s) * D_ + d0);
        float acc = 0.f;
        for (int j = 0; j < 8; ++j)
            acc += tanh_fast(qr[j] + b2f((unsigned short)kv[j])) * var[j];
        for (int o = 32; o >= 1; o >>= 1) acc += __shfl_xor(acc, o);
        if (lane == 0) sc[s] = acc + bvv;
    }
    __syncthreads();
    if (wave == 0) {
        float v0 = sc[lane], v1 = sc[lane + 64];
        float m = fmaxf(v0, v1);
        for (int o = 32; o >= 1; o >>= 1) m = fmaxf(m, __shfl_xor(m, o));
        float e0 = __expf(v0 - m), e1 = __expf(v1 - m);
        float su = e0 + e1;
        for (int o = 32; o >= 1; o >>= 1) su += __shfl_xor(su, o);
        if (lane == 0) { red[0] = m; red[1] = su; }
    }
    __syncthreads();
    {
        float m = red[0], inv = 1.0f / red[1];
        if (t < S_) {
            float w = __expf(sc[t] - m) * inv;
            wbuf[t] = w;
            attn_out[((size_t)b * T_ + tstep) * S_ + t] = w;
        }
    }
    __syncthreads();
    {
        int dd = t * 2;
        float a0 = 0.f, a1 = 0.f;
        const short* ebase = eall + (size_t)b * S_ * D_ + dd;
        #pragma unroll 4
        for (int s = 0; s < S_; ++s) {
            float wv = wbuf[s];
            short2 ev = *(const short2*)(ebase + (size_t)s * D_);
            a0 += wv * b2f((unsigned short)ev.x);
            a1 += wv * b2f((unsigned short)ev.y);
        }
        xcat[(size_t)b * 1536 + 512 + dd]     = (short)f2b(a0);
        xcat[(size_t)b * 1536 + 512 + dd + 1] = (short)f2b(a1);
    }
}

// ---------------- LSTM pointwise + stage next step inputs ----------------
__global__ __launch_bounds__(256)
void lstm_update(const float* __restrict__ g, float* __restrict__ c,
                 short* __restrict__ hcbf, short* __restrict__ xcat,
                 short* __restrict__ h2bf, const float* __restrict__ E,
                 const int* __restrict__ target, int tstep)
{
    int gid = blockIdx.x * 256 + threadIdx.x;
    int b = gid >> 9, d = gid & 511;
    const float* gr = g + (size_t)b * 2048;
    float gi = gr[d], gf = gr[512 + d], gg = gr[1024 + d], go = gr[1536 + d];
    float cv = c[gid];
    float c2 = sigm(gf) * cv + sigm(gi) * tanh_fast(gg);
    float h2 = sigm(go) * tanh_fast(c2);
    c[gid] = c2;
    hcbf[gid] = (short)f2b(h2 + c2);
    h2bf[gid] = (short)f2b(h2);
    xcat[(size_t)b * 1536 + 1024 + d] = (short)f2b(h2);
    int tn = tstep + 1;
    if (tn < T_) {
        int tok = target[b * T_ + tstep];
        xcat[(size_t)b * 1536 + d] = (short)f2b(E[tok * D_ + d]);
    }
}

__global__ __launch_bounds__(256)
void init_state(const float* __restrict__ e_h, const float* __restrict__ e_c,
                float* __restrict__ c, short* __restrict__ hcbf,
                short* __restrict__ xcat, const float* __restrict__ E)
{
    int gid = blockIdx.x * 256 + threadIdx.x;
    int b = gid >> 9, d = gid & 511;
    float h0 = e_h[gid], c0 = e_c[gid];
    c[gid] = c0;
    hcbf[gid] = (short)f2b(h0 + c0);
    xcat[(size_t)b * 1536 + 1024 + d] = (short)f2b(h0);
    xcat[(size_t)b * 1536 + d] = (short)f2b(E[d]);
}

// ---------------- weight transpose + cast: in[K,N] f32 -> out[n][k] bf16 ----------------
__global__ __launch_bounds__(256)
void transpose_cast(const float* __restrict__ in, short* __restrict__ out,
                    int K, int N, int ostride, int koff)
{
    __shared__ float tile[64][65];
    int t = threadIdx.x;
    int n0 = blockIdx.x * 64, k0 = blockIdx.y * 64;
    int cc = t & 63, r4 = t >> 6;
    for (int i = 0; i < 16; ++i) {
        int r = i * 4 + r4;
        tile[r][cc] = in[(size_t)(k0 + r) * N + n0 + cc];
    }
    __syncthreads();
    for (int i = 0; i < 16; ++i) {
        int nr = i * 4 + r4;
        out[(size_t)(n0 + nr) * ostride + koff + k0 + cc] = (short)f2b(tile[cc][nr]);
    }
}

__global__ __launch_bounds__(256)
void cast_bf16_v4(const float* __restrict__ in, short* __restrict__ out, int n4)
{
    int i = blockIdx.x * 256 + threadIdx.x;
    int stride = gridDim.x * 256;
    for (; i < n4; i += stride) {
        f32x4 v = ((const f32x4*)in)[i];
        s16x4 o;
        for (int j = 0; j < 4; ++j) o[j] = (short)f2b(v[j]);
        ((s16x4*)out)[i] = o;
    }
}

__global__ __launch_bounds__(256)
void make_bcat(const float* __restrict__ b_ih, const float* __restrict__ b_hh, float* __restrict__ bcat)
{
    int i = blockIdx.x * 256 + threadIdx.x;
    if (i < 2048) bcat[i] = b_ih[i] + b_hh[i];
}

extern "C" void kernel_launch(void* const* d_in, const int* in_sizes, int n_in,
                              void* d_out, int out_size, void* d_ws, size_t ws_size,
                              hipStream_t stream)
{
    const float* e_all  = (const float*)d_in[0];
    const float* e_h    = (const float*)d_in[1];
    const float* e_c    = (const float*)d_in[2];
    const int*   target = (const int*)d_in[3];
    const float* E      = (const float*)d_in[4];
    const float* Wa     = (const float*)d_in[5];
    const float* ba     = (const float*)d_in[6];
    const float* Ua     = (const float*)d_in[7];
    const float* bu     = (const float*)d_in[8];
    const float* Va     = (const float*)d_in[9];
    const float* bv     = (const float*)d_in[10];
    const float* W_ih   = (const float*)d_in[11];
    const float* b_ih   = (const float*)d_in[12];
    const float* W_hh   = (const float*)d_in[13];
    const float* b_hh   = (const float*)d_in[14];
    const float* W_out  = (const float*)d_in[15];
    const float* b_out  = (const float*)d_in[16];

    char* ws = (char*)d_ws;
    size_t off = 0;
    auto alloc = [&](size_t bytes) { void* p = ws + off; off += (bytes + 255) & ~255ull; return p; };
    short* ealb  = (short*)alloc((size_t)B_ * S_ * D_ * 2);
    short* kpb   = (short*)alloc((size_t)B_ * S_ * D_ * 2);
    short* WaT   = (short*)alloc((size_t)D_ * D_ * 2);
    short* UaT   = (short*)alloc((size_t)D_ * D_ * 2);
    short* WcatT = (short*)alloc((size_t)2048 * 1536 * 2);
    short* WoutT = (short*)alloc((size_t)V_ * D_ * 2);
    float* bcat  = (float*)alloc(2048 * 4);
    float* qb    = (float*)alloc((size_t)B_ * D_ * 4);
    short* xcat  = (short*)alloc((size_t)B_ * 1536 * 2);
    short* hcbf  = (short*)alloc((size_t)B_ * D_ * 2);
    short* h2bf  = (short*)alloc((size_t)B_ * D_ * 2);
    float* cst   = (float*)alloc((size_t)B_ * D_ * 4);
    float* gbuf  = (float*)alloc((size_t)B_ * 2048 * 4);
    if (off > ws_size) return;  // workspace too small; bail (will fail validation visibly)

    float* out_logits = (float*)d_out;                        // [B,T,V]
    float* out_attn   = (float*)d_out + (size_t)B_ * T_ * V_; // [B,T,S]

    // ---- precompute ----
    cast_bf16_v4<<<4096, 256, 0, stream>>>(e_all, ealb, B_ * S_ * D_ / 4);
    transpose_cast<<<dim3(8, 8),   256, 0, stream>>>(Wa,    WaT,   512,  512,  512, 0);
    transpose_cast<<<dim3(8, 8),   256, 0, stream>>>(Ua,    UaT,   512,  512,  512, 0);
    transpose_cast<<<dim3(32, 16), 256, 0, stream>>>(W_ih,  WcatT, 1024, 2048, 1536, 0);
    transpose_cast<<<dim3(32, 8),  256, 0, stream>>>(W_hh,  WcatT, 512,  2048, 1536, 1024);
    transpose_cast<<<dim3(2, 8),   256, 0, stream>>>(W_out, WoutT, 512,  128,  512, 0);
    make_bcat<<<8, 256, 0, stream>>>(b_ih, b_hh, bcat);
    gemm64<true><<<dim3(8, 1024), 256, 0, stream>>>(ealb, UaT, bu, kpb, B_ * S_, 512, 512);
    init_state<<<1024, 256, 0, stream>>>(e_h, e_c, cst, hcbf, xcat, E);

    // ---- sequential decode ----
    for (int t = 0; t < T_; ++t) {
        gemm64<false><<<dim3(8, 8),  256, 0, stream>>>(hcbf, WaT, ba, qb, B_, D_, D_);
        attn_step<<<B_, 256, 0, stream>>>(qb, kpb, ealb, Va, bv, xcat, out_attn, t);
        gemm64<false><<<dim3(32, 8), 256, 0, stream>>>(xcat, WcatT, bcat, gbuf, B_, 2048, 1536);
        lstm_update<<<1024, 256, 0, stream>>>(gbuf, cst, hcbf, xcat, h2bf, E, target, t);
        out_lsm<<<8, 256, 0, stream>>>(h2bf, WoutT, b_out, out_logits, t);
    }
    (void)n_in; (void)in_sizes; (void)out_size;
}

// Round 2
// 9096.069 us; speedup vs baseline: 1.1437x; 1.1437x over previous
//
#include <hip/hip_runtime.h>

#define B_ 512
#define S_ 128
#define T_ 128
#define D_ 512
#define V_ 128

typedef __attribute__((ext_vector_type(8))) short s16x8;
typedef __attribute__((ext_vector_type(4))) short s16x4;
typedef __attribute__((ext_vector_type(4))) float f32x4;

__device__ __forceinline__ float b2f(unsigned short h) {
    union { unsigned int u; float f; } x;
    x.u = ((unsigned int)h) << 16;
    return x.f;
}
__device__ __forceinline__ unsigned short f2b(float f) {
    union { float f; unsigned int u; } x;
    x.f = f;
    unsigned int u = x.u;
    u += 0x7FFFu + ((u >> 16) & 1u);
    return (unsigned short)(u >> 16);
}
__device__ __forceinline__ float sigm(float x) { return 1.0f / (1.0f + __expf(-x)); }
__device__ __forceinline__ float tanh_fast(float x) {
    float e = __expf(-2.0f * fabsf(x));
    float r = (1.0f - e) / (1.0f + e);
    return copysignf(r, x);
}

// ---------------- generic 64x64 MFMA GEMM: C = A[M,K](bf16) @ Bt[N,K]^T (bf16) + bias ----------------
template<bool OUT_BF16>
__global__ __launch_bounds__(256)
void gemm64(const short* __restrict__ A, const short* __restrict__ Bt,
            const float* __restrict__ bias, void* __restrict__ Cp,
            int M, int N, int K)
{
    __shared__ __align__(16) short As[64][72];
    __shared__ __align__(16) short Bs[64][72];
    const int t = threadIdx.x;
    const int lane = t & 63, wave = t >> 6;
    const int wr = wave >> 1, wc = wave & 1;
    const int lrow = lane & 15, kq = lane >> 4;
    const int m0 = blockIdx.y * 64, n0 = blockIdx.x * 64;
    const int srow = t >> 3, sseg = t & 7;

    f32x4 acc[2][2] = {};
    for (int k0 = 0; k0 < K; k0 += 64) {
        s16x8 va0 = *(const s16x8*)(A + (size_t)(m0 + srow) * K + k0 + sseg * 8);
        s16x8 va1 = *(const s16x8*)(A + (size_t)(m0 + srow + 32) * K + k0 + sseg * 8);
        s16x8 vb0 = *(const s16x8*)(Bt + (size_t)(n0 + srow) * K + k0 + sseg * 8);
        s16x8 vb1 = *(const s16x8*)(Bt + (size_t)(n0 + srow + 32) * K + k0 + sseg * 8);
        __syncthreads();
        *(s16x8*)(&As[srow][sseg * 8]) = va0;
        *(s16x8*)(&As[srow + 32][sseg * 8]) = va1;
        *(s16x8*)(&Bs[srow][sseg * 8]) = vb0;
        *(s16x8*)(&Bs[srow + 32][sseg * 8]) = vb1;
        __syncthreads();
        for (int kk = 0; kk < 64; kk += 32) {
            s16x8 af[2], bf[2];
            af[0] = *(const s16x8*)(&As[wr * 32 + lrow][kk + kq * 8]);
            af[1] = *(const s16x8*)(&As[wr * 32 + 16 + lrow][kk + kq * 8]);
            bf[0] = *(const s16x8*)(&Bs[wc * 32 + lrow][kk + kq * 8]);
            bf[1] = *(const s16x8*)(&Bs[wc * 32 + 16 + lrow][kk + kq * 8]);
            for (int m2 = 0; m2 < 2; ++m2)
                for (int n2 = 0; n2 < 2; ++n2)
                    acc[m2][n2] = __builtin_amdgcn_mfma_f32_16x16x32_bf16(af[m2], bf[n2], acc[m2][n2], 0, 0, 0);
        }
    }
    for (int m2 = 0; m2 < 2; ++m2)
        for (int n2 = 0; n2 < 2; ++n2) {
            int col = n0 + wc * 32 + n2 * 16 + lrow;
            float bvv = bias ? bias[col] : 0.0f;
            for (int j = 0; j < 4; ++j) {
                int row = m0 + wr * 32 + m2 * 16 + kq * 4 + j;
                float v = acc[m2][n2][j] + bvv;
                if (OUT_BF16) ((short*)Cp)[(size_t)row * N + col] = (short)f2b(v);
                else          ((float*)Cp)[(size_t)row * N + col] = v;
            }
        }
}

// ---------------- gate GEMM (M=512,N=2048 interleaved,K=1536) + fused LSTM pointwise ----------------
// Weight columns pre-permuted: n' = dim*4 + gate  (gate: 0=i,1=f,2=g,3=o)
__global__ __launch_bounds__(256)
void gate_lstm(const short* __restrict__ A, const short* __restrict__ Bt,
               const float* __restrict__ bias, float* __restrict__ c,
               short* __restrict__ hcbf, short* __restrict__ xcat,
               short* __restrict__ h2bf, const float* __restrict__ E,
               const int* __restrict__ target, int tstep)
{
    __shared__ __align__(16) short As[64][72];
    __shared__ __align__(16) short Bs[64][72];
    __shared__ float gt[64][68];
    const int t = threadIdx.x;
    const int lane = t & 63, wave = t >> 6;
    const int wr = wave >> 1, wc = wave & 1;
    const int lrow = lane & 15, kq = lane >> 4;
    const int m0 = blockIdx.y * 64, n0 = blockIdx.x * 64;
    const int srow = t >> 3, sseg = t & 7;
    const int K = 1536;

    f32x4 acc[2][2] = {};
    for (int k0 = 0; k0 < K; k0 += 64) {
        s16x8 va0 = *(const s16x8*)(A + (size_t)(m0 + srow) * K + k0 + sseg * 8);
        s16x8 va1 = *(const s16x8*)(A + (size_t)(m0 + srow + 32) * K + k0 + sseg * 8);
        s16x8 vb0 = *(const s16x8*)(Bt + (size_t)(n0 + srow) * K + k0 + sseg * 8);
        s16x8 vb1 = *(const s16x8*)(Bt + (size_t)(n0 + srow + 32) * K + k0 + sseg * 8);
        __syncthreads();
        *(s16x8*)(&As[srow][sseg * 8]) = va0;
        *(s16x8*)(&As[srow + 32][sseg * 8]) = va1;
        *(s16x8*)(&Bs[srow][sseg * 8]) = vb0;
        *(s16x8*)(&Bs[srow + 32][sseg * 8]) = vb1;
        __syncthreads();
        for (int kk = 0; kk < 64; kk += 32) {
            s16x8 af[2], bf[2];
            af[0] = *(const s16x8*)(&As[wr * 32 + lrow][kk + kq * 8]);
            af[1] = *(const s16x8*)(&As[wr * 32 + 16 + lrow][kk + kq * 8]);
            bf[0] = *(const s16x8*)(&Bs[wc * 32 + lrow][kk + kq * 8]);
            bf[1] = *(const s16x8*)(&Bs[wc * 32 + 16 + lrow][kk + kq * 8]);
            for (int m2 = 0; m2 < 2; ++m2)
                for (int n2 = 0; n2 < 2; ++n2)
                    acc[m2][n2] = __builtin_amdgcn_mfma_f32_16x16x32_bf16(af[m2], bf[n2], acc[m2][n2], 0, 0, 0);
        }
    }
    // stage fp32 gate tile to LDS
    for (int m2 = 0; m2 < 2; ++m2)
        for (int n2 = 0; n2 < 2; ++n2) {
            int cl = wc * 32 + n2 * 16 + lrow;
            float bvv = bias[n0 + cl];
            for (int j = 0; j < 4; ++j) {
                int rl = wr * 32 + m2 * 16 + kq * 4 + j;
                gt[rl][cl] = acc[m2][n2][j] + bvv;
            }
        }
    __syncthreads();
    // LSTM pointwise: this block owns rows m0..m0+63, dims n0/4..n0/4+15
    const int rl4 = t >> 4, dl = t & 15;
    for (int pass = 0; pass < 4; ++pass) {
        int row = pass * 16 + rl4;
        int b = m0 + row;
        int d = (n0 >> 2) + dl;
        float gi = gt[row][dl * 4 + 0];
        float gf = gt[row][dl * 4 + 1];
        float gg = gt[row][dl * 4 + 2];
        float go = gt[row][dl * 4 + 3];
        float cv = c[(size_t)b * D_ + d];
        float c2 = sigm(gf) * cv + sigm(gi) * tanh_fast(gg);
        float h2 = sigm(go) * tanh_fast(c2);
        c[(size_t)b * D_ + d] = c2;
        hcbf[(size_t)b * D_ + d] = (short)f2b(h2 + c2);
        h2bf[(size_t)b * D_ + d] = (short)f2b(h2);
        xcat[(size_t)b * 1536 + 1024 + d] = (short)f2b(h2);
        int tok = target[b * T_ + tstep];
        xcat[(size_t)b * 1536 + d] = (short)f2b(E[(size_t)tok * D_ + d]);
    }
}

// ---------------- fused: next-step q GEMM (blocks 0..63) + out GEMM w/ log_softmax (blocks 64..71) ----
__global__ __launch_bounds__(256)
void q_out(const short* __restrict__ hcbf, const short* __restrict__ WaT, const float* __restrict__ ba,
           float* __restrict__ qb,
           const short* __restrict__ h2bf, const short* __restrict__ WoutT, const float* __restrict__ b_out,
           float* __restrict__ outp, int tstep)
{
    __shared__ __align__(16) short As[64][72];
    __shared__ __align__(16) short Bs[128][72];
    const int t = threadIdx.x;
    const int lane = t & 63, wave = t >> 6;
    const int lrow = lane & 15, kq = lane >> 4;
    const int srow = t >> 3, sseg = t & 7;

    if (blockIdx.x < 64) {
        // ---- q = hcbf @ WaT^T + ba   (M=N=K=512) ----
        const int m0 = (blockIdx.x >> 3) * 64, n0 = (blockIdx.x & 7) * 64;
        const int wr = wave >> 1, wc = wave & 1;
        f32x4 acc[2][2] = {};
        for (int k0 = 0; k0 < 512; k0 += 64) {
            s16x8 va0 = *(const s16x8*)(hcbf + (size_t)(m0 + srow) * 512 + k0 + sseg * 8);
            s16x8 va1 = *(const s16x8*)(hcbf + (size_t)(m0 + srow + 32) * 512 + k0 + sseg * 8);
            s16x8 vb0 = *(const s16x8*)(WaT + (size_t)(n0 + srow) * 512 + k0 + sseg * 8);
            s16x8 vb1 = *(const s16x8*)(WaT + (size_t)(n0 + srow + 32) * 512 + k0 + sseg * 8);
            __syncthreads();
            *(s16x8*)(&As[srow][sseg * 8]) = va0;
            *(s16x8*)(&As[srow + 32][sseg * 8]) = va1;
            *(s16x8*)(&Bs[srow][sseg * 8]) = vb0;
            *(s16x8*)(&Bs[srow + 32][sseg * 8]) = vb1;
            __syncthreads();
            for (int kk = 0; kk < 64; kk += 32) {
                s16x8 af[2], bf[2];
                af[0] = *(const s16x8*)(&As[wr * 32 + lrow][kk + kq * 8]);
                af[1] = *(const s16x8*)(&As[wr * 32 + 16 + lrow][kk + kq * 8]);
                bf[0] = *(const s16x8*)(&Bs[wc * 32 + lrow][kk + kq * 8]);
                bf[1] = *(const s16x8*)(&Bs[wc * 32 + 16 + lrow][kk + kq * 8]);
                for (int m2 = 0; m2 < 2; ++m2)
                    for (int n2 = 0; n2 < 2; ++n2)
                        acc[m2][n2] = __builtin_amdgcn_mfma_f32_16x16x32_bf16(af[m2], bf[n2], acc[m2][n2], 0, 0, 0);
            }
        }
        for (int m2 = 0; m2 < 2; ++m2)
            for (int n2 = 0; n2 < 2; ++n2) {
                int col = n0 + wc * 32 + n2 * 16 + lrow;
                float bvv = ba[col];
                for (int j = 0; j < 4; ++j) {
                    int row = m0 + wr * 32 + m2 * 16 + kq * 4 + j;
                    qb[(size_t)row * 512 + col] = acc[m2][n2][j] + bvv;
                }
            }
    } else {
        // ---- out = log_softmax(h2bf @ WoutT^T + b_out)   (M=512,N=128,K=512) ----
        const int m0 = (blockIdx.x - 64) * 64;
        f32x4 acc[8] = {};
        for (int k0 = 0; k0 < 512; k0 += 64) {
            s16x8 va0 = *(const s16x8*)(h2bf + (size_t)(m0 + srow) * 512 + k0 + sseg * 8);
            s16x8 va1 = *(const s16x8*)(h2bf + (size_t)(m0 + srow + 32) * 512 + k0 + sseg * 8);
            s16x8 vb[4];
            for (int p = 0; p < 4; ++p)
                vb[p] = *(const s16x8*)(WoutT + (size_t)(srow + p * 32) * 512 + k0 + sseg * 8);
            __syncthreads();
            *(s16x8*)(&As[srow][sseg * 8]) = va0;
            *(s16x8*)(&As[srow + 32][sseg * 8]) = va1;
            for (int p = 0; p < 4; ++p) *(s16x8*)(&Bs[srow + p * 32][sseg * 8]) = vb[p];
            __syncthreads();
            for (int kk = 0; kk < 64; kk += 32) {
                s16x8 a = *(const s16x8*)(&As[wave * 16 + lrow][kk + kq * 8]);
                for (int f = 0; f < 8; ++f) {
                    s16x8 b = *(const s16x8*)(&Bs[f * 16 + lrow][kk + kq * 8]);
                    acc[f] = __builtin_amdgcn_mfma_f32_16x16x32_bf16(a, b, acc[f], 0, 0, 0);
                }
            }
        }
        float colb[8];
        for (int f = 0; f < 8; ++f) colb[f] = b_out[f * 16 + lrow];
        for (int j = 0; j < 4; ++j) {
            float v[8]; float mx = -1e30f;
            for (int f = 0; f < 8; ++f) { v[f] = acc[f][j] + colb[f]; mx = fmaxf(mx, v[f]); }
            for (int o = 1; o < 16; o <<= 1) mx = fmaxf(mx, __shfl_xor(mx, o));
            float sum = 0.f;
            for (int f = 0; f < 8; ++f) sum += __expf(v[f] - mx);
            for (int o = 1; o < 16; o <<= 1) sum += __shfl_xor(sum, o);
            float lse = mx + __logf(sum);
            int row = m0 + wave * 16 + kq * 4 + j;
            float* orow = outp + ((size_t)row * T_ + tstep) * V_;
            for (int f = 0; f < 8; ++f) orow[f * 16 + lrow] = v[f] - lse;
        }
    }
}

// ---------------- attention: scores + softmax + ctx, one block per batch row ----------------
__global__ __launch_bounds__(256)
void attn_step(const float* __restrict__ q, const short* __restrict__ kp,
               const short* __restrict__ eall, const float* __restrict__ Va,
               const float* __restrict__ bvp, short* __restrict__ xcat,
               float* __restrict__ attn_out, int tstep)
{
    const int b = blockIdx.x;
    const int t = threadIdx.x, lane = t & 63, wave = t >> 6;
    __shared__ float sc[S_];
    __shared__ float wbuf[S_];
    __shared__ float red[2];
    const int d0 = lane * 8;
    float qr[8], var[8];
    const float* qrow = q + (size_t)b * D_ + d0;
    for (int j = 0; j < 8; ++j) { qr[j] = qrow[j]; var[j] = Va[d0 + j]; }
    const float bvv = bvp[0];
    for (int i = 0; i < 32; ++i) {
        int s = wave * 32 + i;
        s16x8 kv = *(const s16x8*)(kp + ((size_t)b * S_ + s) * D_ + d0);
        float acc = 0.f;
        for (int j = 0; j < 8; ++j)
            acc += tanh_fast(qr[j] + b2f((unsigned short)kv[j])) * var[j];
        for (int o = 32; o >= 1; o >>= 1) acc += __shfl_xor(acc, o);
        if (lane == 0) sc[s] = acc + bvv;
    }
    __syncthreads();
    if (wave == 0) {
        float v0 = sc[lane], v1 = sc[lane + 64];
        float m = fmaxf(v0, v1);
        for (int o = 32; o >= 1; o >>= 1) m = fmaxf(m, __shfl_xor(m, o));
        float e0 = __expf(v0 - m), e1 = __expf(v1 - m);
        float su = e0 + e1;
        for (int o = 32; o >= 1; o >>= 1) su += __shfl_xor(su, o);
        if (lane == 0) { red[0] = m; red[1] = su; }
    }
    __syncthreads();
    {
        float m = red[0], inv = 1.0f / red[1];
        if (t < S_) {
            float w = __expf(sc[t] - m) * inv;
            wbuf[t] = w;
            attn_out[((size_t)b * T_ + tstep) * S_ + t] = w;
        }
    }
    __syncthreads();
    {
        int dd = t * 2;
        float a0 = 0.f, a1 = 0.f;
        const short* ebase = eall + (size_t)b * S_ * D_ + dd;
        #pragma unroll 4
        for (int s = 0; s < S_; ++s) {
            float wv = wbuf[s];
            short2 ev = *(const short2*)(ebase + (size_t)s * D_);
            a0 += wv * b2f((unsigned short)ev.x);
            a1 += wv * b2f((unsigned short)ev.y);
        }
        xcat[(size_t)b * 1536 + 512 + dd]     = (short)f2b(a0);
        xcat[(size_t)b * 1536 + 512 + dd + 1] = (short)f2b(a1);
    }
}

__global__ __launch_bounds__(256)
void init_state(const float* __restrict__ e_h, const float* __restrict__ e_c,
                float* __restrict__ c, short* __restrict__ hcbf,
                short* __restrict__ xcat, const float* __restrict__ E)
{
    int gid = blockIdx.x * 256 + threadIdx.x;
    int b = gid >> 9, d = gid & 511;
    float h0 = e_h[gid], c0 = e_c[gid];
    c[gid] = c0;
    hcbf[gid] = (short)f2b(h0 + c0);
    xcat[(size_t)b * 1536 + 1024 + d] = (short)f2b(h0);
    xcat[(size_t)b * 1536 + d] = (short)f2b(E[d]);
}

// ---------------- weight transpose + cast: in[K,N] f32 -> out[perm(n)][k] bf16 ----------------
__global__ __launch_bounds__(256)
void transpose_cast(const float* __restrict__ in, short* __restrict__ out,
                    int K, int N, int ostride, int koff, int gate_perm)
{
    __shared__ float tile[64][65];
    int t = threadIdx.x;
    int n0 = blockIdx.x * 64, k0 = blockIdx.y * 64;
    int cc = t & 63, r4 = t >> 6;
    for (int i = 0; i < 16; ++i) {
        int r = i * 4 + r4;
        tile[r][cc] = in[(size_t)(k0 + r) * N + n0 + cc];
    }
    __syncthreads();
    for (int i = 0; i < 16; ++i) {
        int nr = i * 4 + r4;
        int ng = n0 + nr;
        int np = gate_perm ? ((ng & 511) * 4 + (ng >> 9)) : ng;
        out[(size_t)np * ostride + koff + k0 + cc] = (short)f2b(tile[cc][nr]);
    }
}

__global__ __launch_bounds__(256)
void cast_bf16_v4(const float* __restrict__ in, short* __restrict__ out, int n4)
{
    int i = blockIdx.x * 256 + threadIdx.x;
    int stride = gridDim.x * 256;
    for (; i < n4; i += stride) {
        f32x4 v = ((const f32x4*)in)[i];
        s16x4 o;
        for (int j = 0; j < 4; ++j) o[j] = (short)f2b(v[j]);
        ((s16x4*)out)[i] = o;
    }
}

__global__ __launch_bounds__(256)
void make_bcat(const float* __restrict__ b_ih, const float* __restrict__ b_hh, float* __restrict__ bcat)
{
    int i = blockIdx.x * 256 + threadIdx.x;
    if (i < 2048) {
        int np = (i & 511) * 4 + (i >> 9);
        bcat[np] = b_ih[i] + b_hh[i];
    }
}

extern "C" void kernel_launch(void* const* d_in, const int* in_sizes, int n_in,
                              void* d_out, int out_size, void* d_ws, size_t ws_size,
                              hipStream_t stream)
{
    const float* e_all  = (const float*)d_in[0];
    const float* e_h    = (const float*)d_in[1];
    const float* e_c    = (const float*)d_in[2];
    const int*   target = (const int*)d_in[3];
    const float* E      = (const float*)d_in[4];
    const float* Wa     = (const float*)d_in[5];
    const float* ba     = (const float*)d_in[6];
    const float* Ua     = (const float*)d_in[7];
    const float* bu     = (const float*)d_in[8];
    const float* Va     = (const float*)d_in[9];
    const float* bv     = (const float*)d_in[10];
    const float* W_ih   = (const float*)d_in[11];
    const float* b_ih   = (const float*)d_in[12];
    const float* W_hh   = (const float*)d_in[13];
    const float* b_hh   = (const float*)d_in[14];
    const float* W_out  = (const float*)d_in[15];
    const float* b_out  = (const float*)d_in[16];

    char* ws = (char*)d_ws;
    size_t off = 0;
    auto alloc = [&](size_t bytes) { void* p = ws + off; off += (bytes + 255) & ~255ull; return p; };
    short* ealb  = (short*)alloc((size_t)B_ * S_ * D_ * 2);
    short* kpb   = (short*)alloc((size_t)B_ * S_ * D_ * 2);
    short* WaT   = (short*)alloc((size_t)D_ * D_ * 2);
    short* UaT   = (short*)alloc((size_t)D_ * D_ * 2);
    short* WcatT = (short*)alloc((size_t)2048 * 1536 * 2);
    short* WoutT = (short*)alloc((size_t)V_ * D_ * 2);
    float* bcat  = (float*)alloc(2048 * 4);
    float* qb    = (float*)alloc((size_t)B_ * D_ * 4);
    short* xcat  = (short*)alloc((size_t)B_ * 1536 * 2);
    short* hcbf  = (short*)alloc((size_t)B_ * D_ * 2);
    short* h2bf  = (short*)alloc((size_t)B_ * D_ * 2);
    float* cst   = (float*)alloc((size_t)B_ * D_ * 4);
    if (off > ws_size) return;

    float* out_logits = (float*)d_out;                        // [B,T,V]
    float* out_attn   = (float*)d_out + (size_t)B_ * T_ * V_; // [B,T,S]

    // ---- precompute ----
    cast_bf16_v4<<<4096, 256, 0, stream>>>(e_all, ealb, B_ * S_ * D_ / 4);
    transpose_cast<<<dim3(8, 8),   256, 0, stream>>>(Wa,    WaT,   512,  512,  512, 0, 0);
    transpose_cast<<<dim3(8, 8),   256, 0, stream>>>(Ua,    UaT,   512,  512,  512, 0, 0);
    transpose_cast<<<dim3(32, 16), 256, 0, stream>>>(W_ih,  WcatT, 1024, 2048, 1536, 0, 1);
    transpose_cast<<<dim3(32, 8),  256, 0, stream>>>(W_hh,  WcatT, 512,  2048, 1536, 1024, 1);
    transpose_cast<<<dim3(2, 8),   256, 0, stream>>>(W_out, WoutT, 512,  128,  512, 0, 0);
    make_bcat<<<8, 256, 0, stream>>>(b_ih, b_hh, bcat);
    gemm64<true><<<dim3(8, 1024), 256, 0, stream>>>(ealb, UaT, bu, kpb, B_ * S_, 512, 512);
    init_state<<<1024, 256, 0, stream>>>(e_h, e_c, cst, hcbf, xcat, E);
    // initial q for t=0
    gemm64<false><<<dim3(8, 8), 256, 0, stream>>>(hcbf, WaT, ba, qb, B_, 512, 512);

    // ---- sequential decode: 3 kernels per step ----
    for (int t = 0; t < T_; ++t) {
        attn_step<<<B_, 256, 0, stream>>>(qb, kpb, ealb, Va, bv, xcat, out_attn, t);
        gate_lstm<<<dim3(32, 8), 256, 0, stream>>>(xcat, WcatT, bcat, cst, hcbf, xcat, h2bf, E, target, t);
        q_out<<<72, 256, 0, stream>>>(hcbf, WaT, ba, qb, h2bf, WoutT, b_out, out_logits, t);
    }
    (void)n_in; (void)in_sizes; (void)out_size;
}